// Round 6
// baseline (157.229 us; speedup 1.0000x reference)
//
#include <hip/hip_runtime.h>

#define B_ 4096
#define T_ 1024
#define H_ 15

// ===== R3: h-state + Pade[7/6] tanh (one trans op on the chain) =====
// State: h directly (no sigmoid transform). Per step:
//   a = sum_c w_hh[m][c] h[c] + (b_ih+b_hh)[m] + x_t*w_ih[m]
//   h' = tanh(a) ~= ab*N(t)/D(t), ab = clamp(a,-5,5), t = ab^2
//   N = 135135 + 17325 t + 378 t^2 + t^3
//   D = 135135 + 62370 t + 3150 t^2 + 28 t^3      (CF truncation; exact ints)
//   max |err| ~1.0e-4 at |a|=5; 1.5e-5 at |a|=4; tail held at Pade(5)=1.00001.
// Head-fold: lane 15 weights = w_lin, bias = b_lin, wih = 0 -> lane 15's
// 'a' = out[t-1] exactly (f32 linear head), retired one step delayed.
// Lane 15's own h = clamp/Pade of out -- bounded garbage, never consumed
// (every lane's c=15 weight is 0).
//
// MAC: 4 chains (A seeded by plain fma with bs = x*wih+bias; B/C/D pure
// DPP), round-robin for >=4-instr same-chain spacing.
// Tail: Estrin Pade; ONE v_rcp on the chain (exp+add+rcp was two trans
// latencies in series -- the R0..R2 wall was issue(~98) + ~70cy tail chain).
// Split: block A ends after hN=ab*N (rcp in flight); store/refill glue sits
// between A and B filling the rcp shadow; block B: h = hN*rD, s_nop 1
// (2 DPP wait states before next block's first DPP read of h).
#define STEPA(XTN, ODST, HN, RD)                                              \
  do {                                                                        \
    float cA_, cB_, cC_, cD_, t1_, t2s_, ab_, tq_, tq2_, nA_, dA_, nB_, dB_,  \
        N_, D_;                                                               \
    asm("v_mul_f32_dpp %[cB], %[u], %[w1] row_ror:1 row_mask:0xf bank_mask:0xf\n\t"   \
        "v_mul_f32_dpp %[cC], %[u], %[w2] row_ror:2 row_mask:0xf bank_mask:0xf\n\t"   \
        "v_mul_f32_dpp %[cD], %[u], %[w3] row_ror:3 row_mask:0xf bank_mask:0xf\n\t"   \
        "v_fma_f32 %[cA], %[u], %[w0], %[bs]\n\t"                             \
        "v_fmac_f32_dpp %[cB], %[u], %[w5] row_ror:5 row_mask:0xf bank_mask:0xf\n\t"  \
        "v_fmac_f32_dpp %[cC], %[u], %[w6] row_ror:6 row_mask:0xf bank_mask:0xf\n\t"  \
        "v_fmac_f32_dpp %[cD], %[u], %[w7] row_ror:7 row_mask:0xf bank_mask:0xf\n\t"  \
        "v_fmac_f32_dpp %[cA], %[u], %[w4] row_ror:4 row_mask:0xf bank_mask:0xf\n\t"  \
        "v_fmac_f32_dpp %[cB], %[u], %[w9] row_ror:9 row_mask:0xf bank_mask:0xf\n\t"  \
        "v_fmac_f32_dpp %[cC], %[u], %[w10] row_ror:10 row_mask:0xf bank_mask:0xf\n\t" \
        "v_fmac_f32_dpp %[cD], %[u], %[w11] row_ror:11 row_mask:0xf bank_mask:0xf\n\t" \
        "v_fmac_f32_dpp %[cA], %[u], %[w8] row_ror:8 row_mask:0xf bank_mask:0xf\n\t"  \
        "v_fmac_f32_dpp %[cB], %[u], %[w13] row_ror:13 row_mask:0xf bank_mask:0xf\n\t" \
        "v_fmac_f32_dpp %[cC], %[u], %[w14] row_ror:14 row_mask:0xf bank_mask:0xf\n\t" \
        "v_fmac_f32_dpp %[cD], %[u], %[w15] row_ror:15 row_mask:0xf bank_mask:0xf\n\t" \
        "v_fmac_f32_dpp %[cA], %[u], %[w12] row_ror:12 row_mask:0xf bank_mask:0xf\n\t" \
        "v_add_f32 %[t1], %[cB], %[cC]\n\t"                                   \
        "v_fma_f32 %[bs], %[xtn], %[wih], %[bias]\n\t"                        \
        "v_add_f32 %[t2s], %[cD], %[cA]\n\t"                                  \
        "v_add_f32 %[a], %[t1], %[t2s]\n\t"                                   \
        "v_med3_f32 %[ab], %[a], %[m5], %[p5]\n\t"                            \
        "v_mul_f32 %[tq], %[ab], %[ab]\n\t"                                   \
        "v_fma_f32 %[nA], %[tq], %[k17325], %[kBig]\n\t"                      \
        "v_fma_f32 %[dA], %[tq], %[k62370], %[kBig]\n\t"                      \
        "v_mul_f32 %[tq2], %[tq], %[tq]\n\t"                                  \
        "v_add_f32 %[nB], %[tq], %[k378]\n\t"                                 \
        "v_fma_f32 %[dB], %[tq], %[k28], %[k3150]\n\t"                        \
        "v_fma_f32 %[N], %[tq2], %[nB], %[nA]\n\t"                            \
        "v_fma_f32 %[D], %[tq2], %[dB], %[dA]\n\t"                            \
        "v_rcp_f32 %[rD], %[D]\n\t"                                           \
        "v_mul_f32 %[hN], %[ab], %[N]\n\t"                                    \
        : [bs] "+v"(bs), [a] "=&v"(ODST), [hN] "=&v"(HN), [rD] "=&v"(RD),     \
          [cA] "=&v"(cA_), [cB] "=&v"(cB_), [cC] "=&v"(cC_), [cD] "=&v"(cD_), \
          [t1] "=&v"(t1_), [t2s] "=&v"(t2s_), [ab] "=&v"(ab_),                \
          [tq] "=&v"(tq_), [tq2] "=&v"(tq2_), [nA] "=&v"(nA_),                \
          [dA] "=&v"(dA_), [nB] "=&v"(nB_), [dB] "=&v"(dB_), [N] "=&v"(N_),   \
          [D] "=&v"(D_)                                                       \
        : [u] "v"(u), [xtn] "v"(XTN), [wih] "v"(wih2), [bias] "v"(bias2),     \
          [kBig] "v"(kBig), [k17325] "v"(k17325), [k62370] "v"(k62370),       \
          [k378] "v"(k378), [k3150] "v"(k3150), [k28] "v"(k28),               \
          [m5] "v"(m5), [p5] "v"(p5),                                         \
          [w0] "v"(wr[0]), [w1] "v"(wr[1]), [w2] "v"(wr[2]),                  \
          [w3] "v"(wr[3]), [w4] "v"(wr[4]), [w5] "v"(wr[5]),                  \
          [w6] "v"(wr[6]), [w7] "v"(wr[7]), [w8] "v"(wr[8]),                  \
          [w9] "v"(wr[9]), [w10] "v"(wr[10]), [w11] "v"(wr[11]),              \
          [w12] "v"(wr[12]), [w13] "v"(wr[13]), [w14] "v"(wr[14]),            \
          [w15] "v"(wr[15]));                                                 \
  } while (0)

// Finisher: h = hN * rD, then 2 DPP wait states before the next block's
// first DPP read of u (s_nop 1).  Glue (store/refill) between A and B
// fills the rcp latency shadow.
#define STEPB(HN, RD)                                                         \
  asm("v_mul_f32 %[u], %[hN], %[rD]\n\t"                                      \
      "s_nop 1\n\t"                                                           \
      : [u] "=v"(u)                                                           \
      : [hN] "v"(HN), [rD] "v"(RD))

// Pipeline position K (0..31): runs step t+K; XV is x for step t+K+1
// (feeds the in-asm bs prefetch). Lane-15 'a' = out[t+K-1] -> staged at
// (K-1)&3; finished 4-pack stored at K%4==0 (skip the first, garbage,
// retirement); one x buffer refilled per 4 steps (refill-to-use = 28 steps).
#define POS(K, XV)                                                            \
  do {                                                                        \
    float o_, hN_, rD_;                                                       \
    STEPA(XV, o_, hN_, rD_);                                                  \
    osta[((K) + 3) & 3] = o_;                                                 \
    if (((K) & 3) == 0) {                                                     \
      if ((K) > 0 || t > 0) {                                                 \
        if (m == 15)                                                          \
          *(float4*)(ob + t + (K) - 4) =                                      \
              make_float4(osta[0], osta[1], osta[2], osta[3]);                \
      }                                                                       \
    }                                                                         \
    if (((K) & 3) == 3) {                                                     \
      int _tn = t + 32 + (((K) >> 2) << 2);                                   \
      if (_tn >= T_) _tn = 0; /* clamped dummy refill near the end */         \
      qq[(K) >> 2] = *(const float4*)(xb + _tn);                              \
    }                                                                         \
    STEPB(hN_, rD_);                                                          \
  } while (0)

// 16 lanes/batch, 4 batches/wave, 1024 waves = 1 wave/SIMD.
__global__ __attribute__((amdgpu_flat_work_group_size(256, 256),
                          amdgpu_waves_per_eu(1, 1)))
void rnn_tanh_kernel(
    const float* __restrict__ x, const float* __restrict__ w_ih,
    const float* __restrict__ w_hh, const float* __restrict__ b_ih,
    const float* __restrict__ b_hh, const float* __restrict__ w_lin,
    const float* __restrict__ b_lin, float* __restrict__ out) {
  const int tid = threadIdx.x;
  const int m = tid & 15;                      // hidden row (15 = head lane)
  const int b = blockIdx.x * 16 + (tid >> 4);  // batch index

  // Rotation-permuted weights (rot n reads h[(m-n)&15]).
  // Lanes 0..14: recurrence rows (plain). Lane 15: head weights.
  float wr[16];
#pragma unroll
  for (int n = 0; n < 16; ++n) {
    const int c = (m - n) & 15;
    if (m < H_)
      wr[n] = (c < H_) ? w_hh[m * H_ + c] : 0.0f;
    else
      wr[n] = (c < H_) ? w_lin[c] : 0.0f;
  }
  const float wih2  = (m < H_) ? w_ih[m] : 0.0f;
  const float bias2 = (m < H_) ? (b_ih[m] + b_hh[m]) : b_lin[0];

  // Pade[7/6] constants (exact in f32; 28.0f must be a register -- integer
  // inline consts 1..64 are NOT float values).
  const float kBig = 135135.0f, k17325 = 17325.0f, k62370 = 62370.0f;
  const float k378 = 378.0f, k3150 = 3150.0f, k28 = 28.0f;
  const float m5 = -5.0f, p5 = 5.0f;

  const float* xb = x + (size_t)b * T_;
  float* ob = out + (size_t)b * T_;

  float u = 0.0f;  // h0 = 0 (lane 15's h is never consumed)
  asm("s_nop 1" : "+v"(u));  // guard: >=2 wait states before first DPP read
  float osta[4];             // output staging (constant-indexed -> registers)

  // 8-buffer x software pipeline.
  float4 qq[8];
#pragma unroll
  for (int j = 0; j < 8; ++j) qq[j] = *(const float4*)(xb + 4 * j);

  // bs for step 0 (prefetched pattern: STEP consumes current bs, computes next).
  float bs = fmaf(qq[0].x, wih2, bias2);

  for (int t = 0; t < T_; t += 32) {
    POS(0,  qq[0].y); POS(1,  qq[0].z); POS(2,  qq[0].w); POS(3,  qq[1].x);
    POS(4,  qq[1].y); POS(5,  qq[1].z); POS(6,  qq[1].w); POS(7,  qq[2].x);
    POS(8,  qq[2].y); POS(9,  qq[2].z); POS(10, qq[2].w); POS(11, qq[3].x);
    POS(12, qq[3].y); POS(13, qq[3].z); POS(14, qq[3].w); POS(15, qq[4].x);
    POS(16, qq[4].y); POS(17, qq[4].z); POS(18, qq[4].w); POS(19, qq[5].x);
    POS(20, qq[5].y); POS(21, qq[5].z); POS(22, qq[5].w); POS(23, qq[6].x);
    POS(24, qq[6].y); POS(25, qq[6].z); POS(26, qq[6].w); POS(27, qq[7].x);
    POS(28, qq[7].y); POS(29, qq[7].z); POS(30, qq[7].w); POS(31, qq[0].x);
  }

  // Epilogue: one extra STEPA (dummy x feeds only the dead bs prefetch) —
  // its lane-15 'a' reads the final h_{T-1}, producing out[T-1]; complete
  // and store the last 4-pack.
  {
    float o_, hN_, rD_;
    STEPA(0.0f, o_, hN_, rD_);
    osta[3] = o_;
    if (m == 15)
      *(float4*)(ob + T_ - 4) = make_float4(osta[0], osta[1], osta[2], osta[3]);
    (void)hN_; (void)rD_;
  }
}

extern "C" void kernel_launch(void* const* d_in, const int* in_sizes, int n_in,
                              void* d_out, int out_size, void* d_ws, size_t ws_size,
                              hipStream_t stream) {
  (void)in_sizes; (void)n_in; (void)out_size; (void)d_ws; (void)ws_size;
  rnn_tanh_kernel<<<B_ / 16, 256, 0, stream>>>(
      (const float*)d_in[0], (const float*)d_in[1], (const float*)d_in[2],
      (const float*)d_in[3], (const float*)d_in[4], (const float*)d_in[5],
      (const float*)d_in[6], (float*)d_out);
}